// Round 1
// baseline (24023.991 us; speedup 1.0000x reference)
//
#include <hip/hip_runtime.h>
#include <cmath>

// ---------------------------------------------------------------------------
// Liquid NN (CfC) persistent-kernel implementation.
//
// 8 groups x 32 WGs = 256 WGs (1 per CU, forced by 110KB LDS). Group owns 32
// batch rows; WG owns a unit slice of all 3 layers: (5,2,1) or (4,3,1) units
// -> always 32 GEMM cols (8 units x {ff1,ff2,ta,tb}). Layer-skewed pipeline:
// tick k computes h0(k), h1(k-1), h2(k-2) -> one group barrier per tick.
// Weights fp32 (mask folded) resident in LDS; hidden state exchanged via
// global ws with system-scope relaxed atomics (MALL-coherent, XCD-safe).
// ---------------------------------------------------------------------------

constexpr int TT   = 1024;   // sequence length
constexpr int NB   = 256;    // batch
constexpr int GRP  = 8;      // groups
constexpr int WPG  = 32;     // WGs per group
constexpr int NU0  = 135, NU1 = 89, NU2 = 32;
constexpr int CAT0 = 263, CAT1 = 224, CAT2 = 121;
// padded K (mult of 4 for float4; %32 chosen to keep LDS conflicts <=2-way)
constexpr int KP0  = 268, KP1 = 228, KP2 = 124;

// LDS layout (dwords)
constexpr int ZB0s   = 0;
constexpr int ZB1s   = 32 * KP0;            // 8576
constexpr int ZB2s   = ZB1s + 32 * KP1;     // 15872
constexpr int WBASEs = ZB2s + 32 * KP2;     // 19840
constexpr int WMAXs  = 5*4*KP0 + 2*4*KP1 + 1*4*KP2;  // 7680 (max over WG mixes)
constexpr int BBASEs = WBASEs + WMAXs;      // 27520
constexpr int SMEM_DW    = BBASEs + 32;     // 27552
constexpr int SMEM_BYTES = SMEM_DW * 4;     // 110208

// workspace layout (dwords): h exchange double-buffered by tick parity + flags
constexpr int H0_OFF = 0;
constexpr int H0_SZ  = 2 * GRP * NU0 * 32;  // 69120
constexpr int H1_OFF = H0_OFF + H0_SZ;
constexpr int H1_SZ  = 2 * GRP * NU1 * 32;  // 45568
constexpr int H2_OFF = H1_OFF + H1_SZ;
constexpr int H2_SZ  = 2 * GRP * NU2 * 32;  // 16384
constexpr int FLAG_OFF = H2_OFF + H2_SZ;    // 131072
constexpr int FLAG_SZ  = 256 * 16;          // one padded slot per WG
constexpr int WS_DW    = FLAG_OFF + FLAG_SZ;

struct Params {
  const float* x;
  const float* w[3][4];
  const float* b[3][4];
  const int*   mk[3];
  float* h0; float* h1; float* h2;
  int*   flags;
  float* out;
};

__device__ __forceinline__ float sysload(const float* p) {
  return __hip_atomic_load(p, __ATOMIC_RELAXED, __HIP_MEMORY_SCOPE_SYSTEM);
}
__device__ __forceinline__ void sysstore(float* p, float v) {
  __hip_atomic_store(p, v, __ATOMIC_RELAXED, __HIP_MEMORY_SCOPE_SYSTEM);
}

extern "C" __global__ void __launch_bounds__(256, 1)
lnn_main(Params p) {
  extern __shared__ float smem[];
  const int tid   = threadIdx.x;
  const int g     = blockIdx.x & 7;    // group (heuristically XCD-local)
  const int w_idx = blockIdx.x >> 3;   // 0..31 within group

  // ---- per-WG unit slices: 7 WGs get (5,2,1), 25 WGs get (4,3,1) ----------
  const int n0  = (w_idx < 7) ? 5 : 4;
  const int us0 = (w_idx < 7) ? w_idx * 5 : 35 + (w_idx - 7) * 4;
  const int n1  = (w_idx < 7) ? 2 : 3;
  const int us1 = (w_idx < 7) ? w_idx * 2 : 14 + (w_idx - 7) * 3;
  const int us2 = w_idx;

  // ---- load weights (x mask) + bias into LDS, once --------------------------
  for (int c = 0; c < 32; ++c) {
    const int s = c >> 2, m = c & 3;
    int lyr, u_loc, ug, cat, kp, wb;
    if (s < n0)           { lyr = 0; u_loc = s;          ug = us0 + u_loc; cat = CAT0; kp = KP0; wb = (u_loc*4 + m) * KP0; }
    else if (s < n0 + n1) { lyr = 1; u_loc = s - n0;     ug = us1 + u_loc; cat = CAT1; kp = KP1; wb = n0*4*KP0 + (u_loc*4 + m) * KP1; }
    else                  { lyr = 2; u_loc = s - n0 - n1; ug = us2 + u_loc; cat = CAT2; kp = KP2; wb = n0*4*KP0 + n1*4*KP1 + (u_loc*4 + m) * KP2; }
    const float* gw = p.w[lyr][m] + (size_t)ug * cat;
    const int*   gm = (m < 2) ? (p.mk[lyr] + (size_t)ug * cat) : nullptr;
    for (int kk = tid; kk < kp; kk += 256) {
      float v = 0.f;
      if (kk < cat) { v = gw[kk]; if (gm) v *= (float)gm[kk]; }
      smem[WBASEs + wb + kk] = v;
    }
  }
  if (tid < 32) {
    const int c = tid, s = c >> 2, m = c & 3;
    int lyr, ug;
    if (s < n0)           { lyr = 0; ug = us0 + s; }
    else if (s < n0 + n1) { lyr = 1; ug = us1 + (s - n0); }
    else                  { lyr = 2; ug = us2 + (s - n0 - n1); }
    smem[BBASEs + c] = p.b[lyr][m][ug];
  }
  __syncthreads();

  // ---- per-thread GEMM constants -------------------------------------------
  // wave tile: 16 rows x 16 cols; thread tile: 2 rows x 2 cols (same unit)
  const int wave = tid >> 6, lane = tid & 63;
  const int rp = (lane & 7) | ((wave & 1) << 3);        // 0..15
  const int cp = ((lane >> 3) & 7) | ((wave >> 1) << 3); // 0..15
  const int r0 = rp * 2;
  const int s    = cp >> 1;
  const int tsel = cp & 1;        // 0: (ff1,ff2)  1: (ta,tb)
  int lyr, u_loc;
  if (s < n0)           { lyr = 0; u_loc = s; }
  else if (s < n0 + n1) { lyr = 1; u_loc = s - n0; }
  else                  { lyr = 2; u_loc = s - n0 - n1; }
  const int ug  = (lyr == 0) ? us0 + u_loc : (lyr == 1) ? us1 + u_loc : us2 + u_loc;
  const int kp  = (lyr == 0) ? KP0 : (lyr == 1) ? KP1 : KP2;
  const int zb  = (lyr == 0) ? ZB0s : (lyr == 1) ? ZB1s : ZB2s;
  const int wlb = (lyr == 0) ? 0 : (lyr == 1) ? n0*4*KP0 : n0*4*KP0 + n1*4*KP1;
  const int wb0 = WBASEs + wlb + (u_loc * 4 + tsel * 2) * kp;
  const int c0  = s * 4 + tsel * 2;
  float* hb   = (lyr == 0) ? p.h0 : (lyr == 1) ? p.h1 : p.h2;
  const int U = (lyr == 0) ? NU0 : (lyr == 1) ? NU1 : NU2;
  const float bias0 = smem[BBASEs + c0];
  const float bias1 = smem[BBASEs + c0 + 1];
  const int flag_self = (g * WPG + w_idx) * 16;

  // ---- tick loop: k = 0 .. T+1 (skewed: stages A@k, B@k-1, C@k-2) ----------
  for (int k = 0; k < TT + 2; ++k) {
    const int p0 = (k - 1) & 1;   // parity of h0(k-1) / h2(k-3)
    const int p1 = k & 1;         // parity of h1(k-2)

    // -- build z buffers in LDS --
    const int tx = (k < TT) ? k : TT - 1;
    for (int i = tid; i < 1024; i += 256) {            // x -> z0[:,0:128]
      const int r = i >> 5, c4 = i & 31;
      const float4 v = *(const float4*)(p.x + ((size_t)(g * 32 + r) * TT + tx) * 128 + c4 * 4);
      *(float4*)(&smem[r * KP0 + c4 * 4]) = v;
    }
    {
      const float* hb0 = p.h0 + ((size_t)p0 * GRP + g) * NU0 * 32;
      const float* hb1 = p.h1 + ((size_t)p1 * GRP + g) * NU1 * 32;
      const float* hb2 = p.h2 + ((size_t)p0 * GRP + g) * NU2 * 32;
      for (int i = tid; i < 8192; i += 256) {          // 256 units x 32 rows
        const int u = i >> 5, r = i & 31;
        if (u < NU0) {
          const float v = sysload(&hb0[u * 32 + r]);
          smem[r * KP0 + 128 + u] = v;                 // z0 h0-part
          smem[ZB1s + r * KP1 + u] = v;                // z1 h0-part
        } else if (u < NU0 + NU1) {
          const int u1 = u - NU0;
          const float v = sysload(&hb1[u1 * 32 + r]);
          smem[ZB1s + r * KP1 + NU0 + u1] = v;         // z1 h1-part
          smem[ZB2s + r * KP2 + u1] = v;               // z2 h1-part
        } else {
          const int u2 = u - NU0 - NU1;
          const float v = sysload(&hb2[u2 * 32 + r]);
          smem[ZB2s + r * KP2 + NU1 + u2] = v;         // z2 h2-part
        }
      }
    }
    if (tid < 32) {                                    // zero padded K cols
      const int r = tid;
      for (int j = CAT0; j < KP0; ++j) smem[r * KP0 + j] = 0.f;
      for (int j = CAT1; j < KP1; ++j) smem[ZB1s + r * KP1 + j] = 0.f;
      for (int j = CAT2; j < KP2; ++j) smem[ZB2s + r * KP2 + j] = 0.f;
    }
    __syncthreads();

    // -- fused 32x32 GEMM (2r x 2c per thread) --
    float acc00 = bias0, acc01 = bias1, acc10 = bias0, acc11 = bias1;
    {
      const float* zp0 = &smem[zb + r0 * kp];
      const float* zp1 = zp0 + kp;
      const float* wp0 = &smem[wb0];
      const float* wp1 = wp0 + kp;
      #pragma unroll 4
      for (int kk = 0; kk < kp; kk += 4) {
        const float4 a0 = *(const float4*)(zp0 + kk);
        const float4 a1 = *(const float4*)(zp1 + kk);
        const float4 b0 = *(const float4*)(wp0 + kk);
        const float4 b1 = *(const float4*)(wp1 + kk);
        acc00 = fmaf(a0.x, b0.x, fmaf(a0.y, b0.y, fmaf(a0.z, b0.z, fmaf(a0.w, b0.w, acc00))));
        acc01 = fmaf(a0.x, b1.x, fmaf(a0.y, b1.y, fmaf(a0.z, b1.z, fmaf(a0.w, b1.w, acc01))));
        acc10 = fmaf(a1.x, b0.x, fmaf(a1.y, b0.y, fmaf(a1.z, b0.z, fmaf(a1.w, b0.w, acc10))));
        acc11 = fmaf(a1.x, b1.x, fmaf(a1.y, b1.y, fmaf(a1.z, b1.z, fmaf(a1.w, b1.w, acc11))));
      }
    }

    // -- combine: ta/tb thread -> sigmoid, shfl to ff thread (lane+8) --
    float sA = acc00 + acc01, sB = acc10 + acc11;
    sA = 1.f / (1.f + expf(-sA));
    sB = 1.f / (1.f + expf(-sB));
    const float gA = __shfl_down(sA, 8);
    const float gB = __shfl_down(sB, 8);
    if (tsel == 0) {
      const float hA = tanhf(acc00) * (1.f - gA) + gA * tanhf(acc01);
      const float hB = tanhf(acc10) * (1.f - gB) + gB * tanhf(acc11);
      const int tl = k - lyr;               // data timestep for this stage
      if (tl >= 0 && tl < TT) {
        const int par = tl & 1;
        float* dst = hb + ((size_t)((par * GRP + g) * U + ug)) * 32 + r0;
        sysstore(dst, hA);
        sysstore(dst + 1, hB);
        if (lyr == 2) {                     // sequence output (pre-fc)
          p.out[((size_t)(g * 32 + r0) * TT + tl) * 32 + ug] = hA;
          p.out[((size_t)(g * 32 + r0 + 1) * TT + tl) * 32 + ug] = hB;
        }
      }
    }

    // -- group barrier: flag release + poll peers --
    __syncthreads();   // drains vmcnt for all waves' stores before the flag
    if (tid == 0)
      __hip_atomic_store(&p.flags[flag_self], k + 1, __ATOMIC_RELEASE, __HIP_MEMORY_SCOPE_SYSTEM);
    if (k < TT + 1) {
      if (tid < WPG) {
        const int* fp = &p.flags[(g * WPG + tid) * 16];
        while (__hip_atomic_load(fp, __ATOMIC_RELAXED, __HIP_MEMORY_SCOPE_SYSTEM) < k + 1)
          __builtin_amdgcn_s_sleep(1);
      }
      __syncthreads();
    }
  }
}

// in-place fc: out[b,t,:] = h2[b,t,:] @ fc_w.T + fc_b   (pool is identity)
extern "C" __global__ void __launch_bounds__(256)
lnn_fc(float* out, const float* fcw, const float* fcb) {
  __shared__ float w[32 * 33];
  __shared__ float bb[32];
  __shared__ float tile[8 * 32];
  const int tid = threadIdx.x;
  for (int i = tid; i < 1024; i += 256) w[(i >> 5) * 33 + (i & 31)] = fcw[i];
  if (tid < 32) bb[tid] = fcb[tid];
  const size_t base = (size_t)blockIdx.x * 256;
  tile[tid] = out[base + tid];
  __syncthreads();
  const int pp = tid >> 5, o = tid & 31;
  float acc = bb[o];
  #pragma unroll
  for (int u = 0; u < 32; ++u) acc = fmaf(tile[pp * 32 + u], w[o * 33 + u], acc);
  out[base + pp * 32 + o] = acc;
}

extern "C" void kernel_launch(void* const* d_in, const int* in_sizes, int n_in,
                              void* d_out, int out_size, void* d_ws, size_t ws_size,
                              hipStream_t stream) {
  Params p;
  p.x = (const float*)d_in[0];
  const int wi[3] = {1, 10, 19};
  for (int l = 0; l < 3; ++l) {
    for (int m = 0; m < 4; ++m) {
      p.w[l][m] = (const float*)d_in[wi[l] + 2 * m];
      p.b[l][m] = (const float*)d_in[wi[l] + 2 * m + 1];
    }
  }
  p.mk[0] = (const int*)d_in[9];
  p.mk[1] = (const int*)d_in[18];
  p.mk[2] = (const int*)d_in[27];
  float* ws = (float*)d_ws;
  p.h0    = ws + H0_OFF;
  p.h1    = ws + H1_OFF;
  p.h2    = ws + H2_OFF;
  p.flags = (int*)(ws + FLAG_OFF);
  p.out   = (float*)d_out;

  // opt-in to >64KB dynamic LDS (idempotent; not a stream op)
  hipFuncSetAttribute(reinterpret_cast<const void*>(lnn_main),
                      hipFuncAttributeMaxDynamicSharedMemorySize, SMEM_BYTES);
  // zero exchange buffers (h(-1)=0) and barrier flags -- every launch
  hipMemsetAsync(d_ws, 0, (size_t)WS_DW * 4, stream);
  lnn_main<<<dim3(GRP * WPG), dim3(256), SMEM_BYTES, stream>>>(p);
  lnn_fc<<<dim3(NB * TT / 8), dim3(256), 0, stream>>>(
      (float*)d_out, (const float*)d_in[28], (const float*)d_in[29]);
}

// Round 2
// 20822.969 us; speedup vs baseline: 1.1537x; 1.1537x over previous
//
#include <hip/hip_runtime.h>
#include <cmath>

// ---------------------------------------------------------------------------
// Liquid NN (CfC) persistent-kernel implementation, R2.
//
// 8 groups x 32 WGs = 256 WGs (1/CU). Group owns 32 batch rows; WG owns a
// unit slice of all 3 layers -> 32 GEMM cols. Layer-skewed pipeline: tick k
// computes h0(k), h1(k-1), h2(k-2); one group barrier per tick.
// R2 changes vs R1 (which stalled on 8192 scalar system-atomic loads/tick):
//  - h exchange is row-major [r][u] (u padded to x4); consumers use PLAIN
//    float4 loads + float4 LDS stores, fenced per tick with
//    __builtin_amdgcn_fence(ACQUIRE, "") -> buffer_inv (producers write
//    through to MALL via system-scope atomic stores, as in R1).
//  - weight columns remapped at LDS-load time to match padded z layout.
//  - one arrive-counter per group (fetch_add + 1-line poll) instead of 32
//    flag polls.
//  - out written coalesced from the assembled z2 LDS tile (h2(k-3)), one row
//    per WG, 8 x float4 -> removes 4B-scatter write amplification.
// ---------------------------------------------------------------------------

constexpr int TT   = 1024;
constexpr int NB   = 256;
constexpr int GRP  = 8;
constexpr int WPG  = 32;
constexpr int NU0  = 135, NU1 = 89, NU2 = 32;
constexpr int CAT0 = 263, CAT1 = 224, CAT2 = 121;
// padded unit counts for the [r][u] exchange layout
constexpr int U0P = 136, U1P = 92, U2P = 32;
// padded K: z0=[x(128)|h0(136,last=0)]+tail4 ; z1=[h0(136)|h1(92)] ; z2=[h1(92)|h2(32)]
constexpr int KP0  = 268, KP1 = 228, KP2 = 124;

// LDS layout (dwords)
constexpr int ZB0s   = 0;
constexpr int ZB1s   = 32 * KP0;            // 8576
constexpr int ZB2s   = ZB1s + 32 * KP1;     // 15872
constexpr int WBASEs = ZB2s + 32 * KP2;     // 19840
constexpr int WMAXs  = 5*4*KP0 + 2*4*KP1 + 1*4*KP2;  // 7680
constexpr int BBASEs = WBASEs + WMAXs;      // 27520
constexpr int SMEM_DW    = BBASEs + 32;     // 27552
constexpr int SMEM_BYTES = SMEM_DW * 4;     // 110208

// workspace layout (dwords): [parity][group][row][u_padded] + arrive counters
constexpr int H0_OFF = 0;
constexpr int H0_SZ  = 2 * GRP * 32 * U0P;  // 69632
constexpr int H1_OFF = H0_OFF + H0_SZ;
constexpr int H1_SZ  = 2 * GRP * 32 * U1P;  // 47104
constexpr int H2_OFF = H1_OFF + H1_SZ;
constexpr int H2_SZ  = 2 * GRP * 32 * U2P;  // 16384
constexpr int CTR_OFF = H2_OFF + H2_SZ;     // 133120
constexpr int CTR_SZ  = GRP * 16;           // 64B-padded counters
constexpr int WS_DW   = CTR_OFF + CTR_SZ;   // 133248

struct Params {
  const float* x;
  const float* w[3][4];
  const float* b[3][4];
  const int*   mk[3];
  float* h0; float* h1; float* h2;
  int*   ctr;
  float* out;
};

__device__ __forceinline__ void sysstore(float* p, float v) {
  __hip_atomic_store(p, v, __ATOMIC_RELAXED, __HIP_MEMORY_SCOPE_SYSTEM);
}

extern "C" __global__ void __launch_bounds__(256, 1)
lnn_main(Params p) {
  extern __shared__ float smem[];
  const int tid   = threadIdx.x;
  const int g     = blockIdx.x & 7;
  const int w_idx = blockIdx.x >> 3;

  // ---- per-WG unit slices: 7 WGs get (5,2,1), 25 WGs get (4,3,1) ----------
  const int n0  = (w_idx < 7) ? 5 : 4;
  const int us0 = (w_idx < 7) ? w_idx * 5 : 35 + (w_idx - 7) * 4;
  const int n1  = (w_idx < 7) ? 2 : 3;
  const int us1 = (w_idx < 7) ? w_idx * 2 : 14 + (w_idx - 7) * 3;
  const int us2 = w_idx;

  // ---- load weights (x mask) into LDS with padded-K remap ------------------
  for (int c = 0; c < 32; ++c) {
    const int s = c >> 2, m = c & 3;
    int lyr, u_loc, ug, cat, kp, wb;
    if (s < n0)           { lyr = 0; u_loc = s;          ug = us0 + u_loc; cat = CAT0; kp = KP0; wb = (u_loc*4 + m) * KP0; }
    else if (s < n0 + n1) { lyr = 1; u_loc = s - n0;     ug = us1 + u_loc; cat = CAT1; kp = KP1; wb = n0*4*KP0 + (u_loc*4 + m) * KP1; }
    else                  { lyr = 2; u_loc = s - n0 - n1; ug = us2 + u_loc; cat = CAT2; kp = KP2; wb = n0*4*KP0 + n1*4*KP1 + (u_loc*4 + m) * KP2; }
    const float* gw = p.w[lyr][m] + (size_t)ug * cat;
    const int*   gm = (m < 2) ? (p.mk[lyr] + (size_t)ug * cat) : nullptr;
    for (int kk = tid; kk < kp; kk += 256) {
      // map padded z index -> original concat index (or -1 for pad)
      int src;
      if (lyr == 0)      src = (kk < 263) ? kk : -1;                    // x|h0, pad h0[135]=0 & tail
      else if (lyr == 1) src = (kk < 135) ? kk : (kk >= 136 && kk < 225) ? kk - 1 : -1;
      else               src = (kk < 89)  ? kk : (kk >= 92  && kk < 124) ? kk - 3 : -1;
      float v = 0.f;
      if (src >= 0) { v = gw[src]; if (gm) v *= (float)gm[src]; }
      smem[WBASEs + wb + kk] = v;
    }
  }
  if (tid < 32) {
    const int c = tid, s = c >> 2, m = c & 3;
    int lyr, ug;
    if (s < n0)           { lyr = 0; ug = us0 + s; }
    else if (s < n0 + n1) { lyr = 1; ug = us1 + (s - n0); }
    else                  { lyr = 2; ug = us2 + (s - n0 - n1); }
    smem[BBASEs + c] = p.b[lyr][m][ug];
    // one-time zero of z0 tail [264..267] (never touched by f4 fills)
    for (int j = 264; j < 268; ++j) smem[tid * KP0 + j] = 0.f;
  }
  __syncthreads();

  // ---- per-thread GEMM constants -------------------------------------------
  const int wave = tid >> 6, lane = tid & 63;
  const int rp = (lane & 7) | ((wave & 1) << 3);
  const int cp = ((lane >> 3) & 7) | ((wave >> 1) << 3);
  const int r0 = rp * 2;
  const int s    = cp >> 1;
  const int tsel = cp & 1;
  int lyr, u_loc;
  if (s < n0)           { lyr = 0; u_loc = s; }
  else if (s < n0 + n1) { lyr = 1; u_loc = s - n0; }
  else                  { lyr = 2; u_loc = s - n0 - n1; }
  const int ug  = (lyr == 0) ? us0 + u_loc : (lyr == 1) ? us1 + u_loc : us2 + u_loc;
  const int kp  = (lyr == 0) ? KP0 : (lyr == 1) ? KP1 : KP2;
  const int zb  = (lyr == 0) ? ZB0s : (lyr == 1) ? ZB1s : ZB2s;
  const int wlb = (lyr == 0) ? 0 : (lyr == 1) ? n0*4*KP0 : n0*4*KP0 + n1*4*KP1;
  const int wb0 = WBASEs + wlb + (u_loc * 4 + tsel * 2) * kp;
  const int c0  = s * 4 + tsel * 2;
  float* hb    = (lyr == 0) ? p.h0 : (lyr == 1) ? p.h1 : p.h2;
  const int UP = (lyr == 0) ? U0P : (lyr == 1) ? U1P : U2P;
  const float bias0 = smem[BBASEs + c0];
  const float bias1 = smem[BBASEs + c0 + 1];

  // ---- tick loop: k = 0 .. TT+2 (A@k, B@k-1, C@k-2, out-copy@k-3) ----------
  for (int k = 0; k < TT + 3; ++k) {
    const int p0 = (k - 1) & 1;   // parity holding h0(k-1) / h2(k-3)
    const int p1 = k & 1;         // parity holding h1(k-2)

    // -- z build: all plain float4 loads + float4 LDS stores --
    const int tx = (k < TT) ? k : TT - 1;
    for (int i = tid; i < 1024; i += 256) {
      const int r = i >> 5, c4 = (i & 31) * 4;
      const float4 v = *(const float4*)(p.x + ((size_t)(g * 32 + r) * TT + tx) * 128 + c4);
      *(float4*)(&smem[r * KP0 + c4]) = v;
    }
    {
      const float* hb0 = p.h0 + (size_t)(p0 * GRP + g) * 32 * U0P;
      for (int i = tid; i < 34 * 32; i += 256) {
        const int r = i / 34, u4 = (i - r * 34) * 4;
        const float4 v = *(const float4*)(hb0 + r * U0P + u4);
        *(float4*)(&smem[r * KP0 + 128 + u4]) = v;     // z0 h0-part
        *(float4*)(&smem[ZB1s + r * KP1 + u4]) = v;    // z1 h0-part
      }
      const float* hb1 = p.h1 + (size_t)(p1 * GRP + g) * 32 * U1P;
      for (int i = tid; i < 23 * 32; i += 256) {
        const int r = i / 23, u4 = (i - r * 23) * 4;
        const float4 v = *(const float4*)(hb1 + r * U1P + u4);
        *(float4*)(&smem[ZB1s + r * KP1 + 136 + u4]) = v;  // z1 h1-part
        *(float4*)(&smem[ZB2s + r * KP2 + u4]) = v;        // z2 h1-part
      }
      const float* hb2 = p.h2 + (size_t)(p0 * GRP + g) * 32 * U2P;
      for (int i = tid; i < 8 * 32; i += 256) {
        const int r = i >> 3, u4 = (i & 7) * 4;
        const float4 v = *(const float4*)(hb2 + r * U2P + u4);
        *(float4*)(&smem[ZB2s + r * KP2 + 92 + u4]) = v;   // z2 h2-part
      }
    }
    __syncthreads();

    // -- coalesced out write: h2(k-3) sits assembled in z2; WG w owns row w --
    if (tid < 8 && k >= 3) {
      const float4 v = *(const float4*)(&smem[ZB2s + w_idx * KP2 + 92 + tid * 4]);
      *(float4*)(&p.out[((size_t)(g * 32 + w_idx) * TT + (k - 3)) * 32 + tid * 4]) = v;
    }

    // -- fused 32x32 GEMM (2r x 2c per thread) --
    float acc00 = bias0, acc01 = bias1, acc10 = bias0, acc11 = bias1;
    {
      const float* zp0 = &smem[zb + r0 * kp];
      const float* zp1 = zp0 + kp;
      const float* wp0 = &smem[wb0];
      const float* wp1 = wp0 + kp;
      #pragma unroll 8
      for (int kk = 0; kk < kp; kk += 4) {
        const float4 a0 = *(const float4*)(zp0 + kk);
        const float4 a1 = *(const float4*)(zp1 + kk);
        const float4 b0 = *(const float4*)(wp0 + kk);
        const float4 b1 = *(const float4*)(wp1 + kk);
        acc00 = fmaf(a0.x, b0.x, fmaf(a0.y, b0.y, fmaf(a0.z, b0.z, fmaf(a0.w, b0.w, acc00))));
        acc01 = fmaf(a0.x, b1.x, fmaf(a0.y, b1.y, fmaf(a0.z, b1.z, fmaf(a0.w, b1.w, acc01))));
        acc10 = fmaf(a1.x, b0.x, fmaf(a1.y, b0.y, fmaf(a1.z, b0.z, fmaf(a1.w, b0.w, acc10))));
        acc11 = fmaf(a1.x, b1.x, fmaf(a1.y, b1.y, fmaf(a1.z, b1.z, fmaf(a1.w, b1.w, acc11))));
      }
    }

    // -- combine: ta/tb thread -> sigmoid, shfl to ff thread --
    float sA = acc00 + acc01, sB = acc10 + acc11;
    sA = 1.f / (1.f + expf(-sA));
    sB = 1.f / (1.f + expf(-sB));
    const float gA = __shfl_down(sA, 8);
    const float gB = __shfl_down(sB, 8);
    if (tsel == 0) {
      const float hA = tanhf(acc00) * (1.f - gA) + gA * tanhf(acc01);
      const float hB = tanhf(acc10) * (1.f - gB) + gB * tanhf(acc11);
      const int tl = k - lyr;
      if (tl >= 0 && tl < TT) {
        const int par = tl & 1;
        float* dst = hb + (size_t)((par * GRP + g) * 32) * UP + ug;
        sysstore(dst + (size_t)r0 * UP, hA);            // write-through to MALL
        sysstore(dst + (size_t)(r0 + 1) * UP, hB);
      }
    }

    // -- group barrier: one arrive-counter per group --
    __syncthreads();   // drains vmcnt (all waves' stores at MALL) before arrive
    if (k < TT + 2) {
      if (tid == 0) {
        int* ctr = p.ctr + g * 16;
        __hip_atomic_fetch_add(ctr, 1, __ATOMIC_RELEASE, __HIP_MEMORY_SCOPE_SYSTEM);
        const int tgt = WPG * (k + 1);
        while (__hip_atomic_load(ctr, __ATOMIC_RELAXED, __HIP_MEMORY_SCOPE_SYSTEM) < tgt)
          __builtin_amdgcn_s_sleep(2);
      }
      __syncthreads();
      // acquire: buffer_inv -> drop stale L1/L2 lines so plain h loads see MALL
      __builtin_amdgcn_fence(__ATOMIC_ACQUIRE, "");
    }
  }
}

// in-place fc: out[b,t,:] = out[b,t,:] @ fc_w.T + fc_b  (pool is identity)
extern "C" __global__ void __launch_bounds__(256)
lnn_fc(float* out, const float* fcw, const float* fcb) {
  __shared__ float w[32 * 33];
  __shared__ float bb[32];
  __shared__ float tile[8 * 32];
  const int tid = threadIdx.x;
  for (int i = tid; i < 1024; i += 256) w[(i >> 5) * 33 + (i & 31)] = fcw[i];
  if (tid < 32) bb[tid] = fcb[tid];
  const size_t base = (size_t)blockIdx.x * 256;
  tile[tid] = out[base + tid];
  __syncthreads();
  const int pp = tid >> 5, o = tid & 31;
  float acc = bb[o];
  #pragma unroll
  for (int u = 0; u < 32; ++u) acc = fmaf(tile[pp * 32 + u], w[o * 33 + u], acc);
  out[base + pp * 32 + o] = acc;
}

extern "C" void kernel_launch(void* const* d_in, const int* in_sizes, int n_in,
                              void* d_out, int out_size, void* d_ws, size_t ws_size,
                              hipStream_t stream) {
  Params p;
  p.x = (const float*)d_in[0];
  const int wi[3] = {1, 10, 19};
  for (int l = 0; l < 3; ++l) {
    for (int m = 0; m < 4; ++m) {
      p.w[l][m] = (const float*)d_in[wi[l] + 2 * m];
      p.b[l][m] = (const float*)d_in[wi[l] + 2 * m + 1];
    }
  }
  p.mk[0] = (const int*)d_in[9];
  p.mk[1] = (const int*)d_in[18];
  p.mk[2] = (const int*)d_in[27];
  float* ws = (float*)d_ws;
  p.h0  = ws + H0_OFF;
  p.h1  = ws + H1_OFF;
  p.h2  = ws + H2_OFF;
  p.ctr = (int*)(ws + CTR_OFF);
  p.out = (float*)d_out;

  hipFuncSetAttribute(reinterpret_cast<const void*>(lnn_main),
                      hipFuncAttributeMaxDynamicSharedMemorySize, SMEM_BYTES);
  hipMemsetAsync(d_ws, 0, (size_t)WS_DW * 4, stream);
  lnn_main<<<dim3(GRP * WPG), dim3(256), SMEM_BYTES, stream>>>(p);
  lnn_fc<<<dim3(NB * TT / 8), dim3(256), 0, stream>>>(
      (float*)d_out, (const float*)d_in[28], (const float*)d_in[29]);
}

// Round 3
// 11817.441 us; speedup vs baseline: 2.0329x; 1.7621x over previous
//
#include <hip/hip_runtime.h>
#include <cmath>

// ---------------------------------------------------------------------------
// Liquid NN (CfC) persistent-kernel implementation, R3.
//
// 8 groups x 32 WGs = 256 WGs (1/CU). Group owns 32 batch rows; WG owns a
// unit slice of all 3 layers -> 32 GEMM cols. Layer-skewed pipeline: tick k
// computes h0(k), h1(k-1), h2(k-2); one group barrier per tick.
// R3 vs R2 (R2 stalled ~13us/tick on per-tick buffer_wbl2/buffer_inv from
// RELEASE atomics + ACQUIRE fence):
//  - ZERO cache-maintenance ops. Producers: per-op sc0/sc1 write-through
//    stores (as before). Consumers: inline-asm global_load_dwordx4 sc0 sc1
//    (coherent f4 loads from MALL), batched issue + single vmcnt(0).
//  - Barrier: RELAXED fetch_add + RELAXED poll, no fences. Producer stores
//    are drained (vmcnt0 at __syncthreads) before the arrive-add issues.
//  - h exchange packed per (parity,group) into one flat block
//    [h0 32x136 | h1 32x92 | h2 32x32] = 8320 floats for flat f4 indexing.
//  - Weight LDS row strides 280/232/136 (==8 mod 16) to break the 4-way
//    bank conflict on GEMM weight reads (2*268 == 24 mod 32).
// ---------------------------------------------------------------------------

constexpr int TT   = 1024;
constexpr int NB   = 256;
constexpr int GRP  = 8;
constexpr int WPG  = 32;
constexpr int NU0  = 135, NU1 = 89, NU2 = 32;
constexpr int CAT0 = 263, CAT1 = 224, CAT2 = 121;
constexpr int U0P = 136, U1P = 92, U2P = 32;
// z-buffer K (row strides): z0=[x 128|h0 136]+4 ; z1=[h0 136|h1 92] ; z2=[h1 92|h2 32]
constexpr int KP0  = 268, KP1 = 228, KP2 = 124;
// weight LDS row strides (>= KP, ==8 mod 16 for conflict-free pairing)
constexpr int WS0  = 280, WS1 = 232, WS2 = 136;

// LDS layout (dwords)
constexpr int ZB0s   = 0;
constexpr int ZB1s   = 32 * KP0;            // 8576
constexpr int ZB2s   = ZB1s + 32 * KP1;     // 15872
constexpr int WBASEs = ZB2s + 32 * KP2;     // 19840
constexpr int WMAXs  = 5*4*WS0 + 2*4*WS1 + 1*4*WS2;  // 8000 (max over WG mixes)
constexpr int BBASEs = WBASEs + WMAXs;      // 27840
constexpr int SMEM_DW    = BBASEs + 32;     // 27872
constexpr int SMEM_BYTES = SMEM_DW * 4;     // 111488

// exchange block per (parity,group): [h0 32x136 | h1 32x92 | h2 32x32]
constexpr int HBLK   = 32*U0P + 32*U1P + 32*U2P;  // 8320 floats = 2080 f4
constexpr int SEG1   = 32*U0P;                     // 4352
constexpr int SEG2   = SEG1 + 32*U1P;              // 7296
constexpr int HTOT_F4 = HBLK / 4;                  // 2080
constexpr int CTR_OFF = 2 * GRP * HBLK;            // 133120 dwords
constexpr int WS_DW   = CTR_OFF + GRP * 16;        // 133248

struct Params {
  const float* x;
  const float* w[3][4];
  const float* b[3][4];
  const int*   mk[3];
  float* hx;      // exchange blocks
  int*   ctr;
  float* out;
};

__device__ __forceinline__ void sysstore(float* p, float v) {
  __hip_atomic_store(p, v, __ATOMIC_RELAXED, __HIP_MEMORY_SCOPE_SYSTEM);
}
// coherent (MALL-snooping) float4 load; value NOT ready until cwait()
__device__ __forceinline__ float4 cload(const float4* p) {
  float4 v;
  asm volatile("global_load_dwordx4 %0, %1, off sc0 sc1"
               : "=v"(v) : "v"(p) : "memory");
  return v;
}
__device__ __forceinline__ void cwait() {
  asm volatile("s_waitcnt vmcnt(0)" ::: "memory");
}

extern "C" __global__ void __launch_bounds__(256, 1)
lnn_main(Params p) {
  extern __shared__ float smem[];
  const int tid   = threadIdx.x;
  const int g     = blockIdx.x & 7;
  const int w_idx = blockIdx.x >> 3;

  // ---- per-WG unit slices: 7 WGs get (5,2,1), 25 WGs get (4,3,1) ----------
  const int n0  = (w_idx < 7) ? 5 : 4;
  const int us0 = (w_idx < 7) ? w_idx * 5 : 35 + (w_idx - 7) * 4;
  const int n1  = (w_idx < 7) ? 2 : 3;
  const int us1 = (w_idx < 7) ? w_idx * 2 : 14 + (w_idx - 7) * 3;
  const int us2 = w_idx;

  // ---- load weights (x mask) into LDS with padded-K remap ------------------
  for (int c = 0; c < 32; ++c) {
    const int s = c >> 2, m = c & 3;
    int lyr, u_loc, ug, cat, kp, ws, wb;
    if (s < n0)           { lyr = 0; u_loc = s;           ug = us0 + u_loc; cat = CAT0; kp = KP0; ws = WS0; wb = (u_loc*4 + m) * WS0; }
    else if (s < n0 + n1) { lyr = 1; u_loc = s - n0;      ug = us1 + u_loc; cat = CAT1; kp = KP1; ws = WS1; wb = n0*4*WS0 + (u_loc*4 + m) * WS1; }
    else                  { lyr = 2; u_loc = s - n0 - n1; ug = us2 + u_loc; cat = CAT2; kp = KP2; ws = WS2; wb = n0*4*WS0 + n1*4*WS1 + (u_loc*4 + m) * WS2; }
    (void)ws;
    const float* gw = p.w[lyr][m] + (size_t)ug * cat;
    const int*   gm = (m < 2) ? (p.mk[lyr] + (size_t)ug * cat) : nullptr;
    for (int kk = tid; kk < kp; kk += 256) {
      int src;
      if (lyr == 0)      src = (kk < 263) ? kk : -1;
      else if (lyr == 1) src = (kk < 135) ? kk : (kk >= 136 && kk < 225) ? kk - 1 : -1;
      else               src = (kk < 89)  ? kk : (kk >= 92  && kk < 124) ? kk - 3 : -1;
      float v = 0.f;
      if (src >= 0) { v = gw[src]; if (gm) v *= (float)gm[src]; }
      smem[WBASEs + wb + kk] = v;
    }
  }
  if (tid < 32) {
    const int c = tid, s = c >> 2, m = c & 3;
    int lyr, ug;
    if (s < n0)           { lyr = 0; ug = us0 + s; }
    else if (s < n0 + n1) { lyr = 1; ug = us1 + (s - n0); }
    else                  { lyr = 2; ug = us2 + (s - n0 - n1); }
    smem[BBASEs + c] = p.b[lyr][m][ug];
    for (int j = 264; j < 268; ++j) smem[tid * KP0 + j] = 0.f;  // z0 tail
  }
  __syncthreads();

  // ---- per-thread GEMM constants -------------------------------------------
  const int wave = tid >> 6, lane = tid & 63;
  const int rp = (lane & 7) | ((wave & 1) << 3);
  const int cp = ((lane >> 3) & 7) | ((wave >> 1) << 3);
  const int r0 = rp * 2;
  const int s    = cp >> 1;
  const int tsel = cp & 1;
  int lyr, u_loc;
  if (s < n0)           { lyr = 0; u_loc = s; }
  else if (s < n0 + n1) { lyr = 1; u_loc = s - n0; }
  else                  { lyr = 2; u_loc = s - n0 - n1; }
  const int ug  = (lyr == 0) ? us0 + u_loc : (lyr == 1) ? us1 + u_loc : us2 + u_loc;
  const int kp  = (lyr == 0) ? KP0 : (lyr == 1) ? KP1 : KP2;
  const int wst = (lyr == 0) ? WS0 : (lyr == 1) ? WS1 : WS2;
  const int zb  = (lyr == 0) ? ZB0s : (lyr == 1) ? ZB1s : ZB2s;
  const int wlb = (lyr == 0) ? 0 : (lyr == 1) ? n0*4*WS0 : n0*4*WS0 + n1*4*WS1;
  const int wb0 = WBASEs + wlb + (u_loc * 4 + tsel * 2) * wst;
  const int c0  = s * 4 + tsel * 2;
  const int seg = (lyr == 0) ? 0 : (lyr == 1) ? SEG1 : SEG2;
  const int UP  = (lyr == 0) ? U0P : (lyr == 1) ? U1P : U2P;
  const float bias0 = smem[BBASEs + c0];
  const float bias1 = smem[BBASEs + c0 + 1];

  // ---- tick loop: k = 0 .. TT+2 (A@k, B@k-1, C@k-2, out-copy@k-3) ----------
  for (int k = 0; k < TT + 3; ++k) {
    const int p0 = (k - 1) & 1;   // parity holding h0(k-1) / h2(k-3)
    const int p1 = k & 1;         // parity holding h1(k-2)

    // -- coherent h loads: issue all, then one wait --
    const float4* hx0 = (const float4*)(p.hx + (size_t)(p0 * GRP + g) * HBLK);
    const float4* hx1 = (const float4*)(p.hx + (size_t)(p1 * GRP + g) * HBLK);
    float4 hv[8];
    #pragma unroll
    for (int it = 0; it < 8; ++it) {
      const int i = tid + it * 256;
      const float4* src = (i >= 1088 && i < 1824) ? hx1 + i : hx0 + i;
      hv[it] = cload(src);
    }
    float4 hvt;
    const bool tail = (tid < HTOT_F4 - 2048);
    if (tail) hvt = cload(hx0 + 2048 + tid);

    // -- x copy (plain loads; compiler-managed waits are position-safe) --
    const int tx = (k < TT) ? k : TT - 1;
    for (int i = tid; i < 1024; i += 256) {
      const int r = i >> 5, c4 = (i & 31) * 4;
      const float4 v = *(const float4*)(p.x + ((size_t)(g * 32 + r) * TT + tx) * 128 + c4);
      *(float4*)(&smem[r * KP0 + c4]) = v;
    }

    cwait();

    // -- scatter h to LDS (dual stores for shared segments) --
    #pragma unroll
    for (int it = 0; it < 8; ++it) {
      const int i = tid + it * 256;
      const float4 v = hv[it];
      if (i < 1088) {
        const int r = i / 34, c4 = (i - r * 34) * 4;
        *(float4*)(&smem[r * KP0 + 128 + c4]) = v;
        *(float4*)(&smem[ZB1s + r * KP1 + c4]) = v;
      } else if (i < 1824) {
        const int j = i - 1088;
        const int r = j / 23, c4 = (j - r * 23) * 4;
        *(float4*)(&smem[ZB1s + r * KP1 + 136 + c4]) = v;
        *(float4*)(&smem[ZB2s + r * KP2 + c4]) = v;
      } else {
        const int j = i - 1824;
        const int r = j >> 3, c4 = (j & 7) * 4;
        *(float4*)(&smem[ZB2s + r * KP2 + 92 + c4]) = v;
      }
    }
    if (tail) {
      const int j = 2048 + tid - 1824;
      const int r = j >> 3, c4 = (j & 7) * 4;
      *(float4*)(&smem[ZB2s + r * KP2 + 92 + c4]) = hvt;
    }
    __syncthreads();

    // -- coalesced out write: h2(k-3) sits assembled in z2; WG w owns row w --
    if (tid < 8 && k >= 3) {
      const float4 v = *(const float4*)(&smem[ZB2s + w_idx * KP2 + 92 + tid * 4]);
      *(float4*)(&p.out[((size_t)(g * 32 + w_idx) * TT + (k - 3)) * 32 + tid * 4]) = v;
    }

    // -- fused 32x32 GEMM (2r x 2c per thread) --
    float acc00 = bias0, acc01 = bias1, acc10 = bias0, acc11 = bias1;
    {
      const float* zp0 = &smem[zb + r0 * kp];
      const float* zp1 = zp0 + kp;
      const float* wp0 = &smem[wb0];
      const float* wp1 = wp0 + wst;
      #pragma unroll 8
      for (int kk = 0; kk < kp; kk += 4) {
        const float4 a0 = *(const float4*)(zp0 + kk);
        const float4 a1 = *(const float4*)(zp1 + kk);
        const float4 b0 = *(const float4*)(wp0 + kk);
        const float4 b1 = *(const float4*)(wp1 + kk);
        acc00 = fmaf(a0.x, b0.x, fmaf(a0.y, b0.y, fmaf(a0.z, b0.z, fmaf(a0.w, b0.w, acc00))));
        acc01 = fmaf(a0.x, b1.x, fmaf(a0.y, b1.y, fmaf(a0.z, b1.z, fmaf(a0.w, b1.w, acc01))));
        acc10 = fmaf(a1.x, b0.x, fmaf(a1.y, b0.y, fmaf(a1.z, b0.z, fmaf(a1.w, b0.w, acc10))));
        acc11 = fmaf(a1.x, b1.x, fmaf(a1.y, b1.y, fmaf(a1.z, b1.z, fmaf(a1.w, b1.w, acc11))));
      }
    }

    // -- combine: ta/tb thread -> sigmoid, shfl to ff thread --
    float sA = acc00 + acc01, sB = acc10 + acc11;
    sA = 1.f / (1.f + expf(-sA));
    sB = 1.f / (1.f + expf(-sB));
    const float gA = __shfl_down(sA, 8);
    const float gB = __shfl_down(sB, 8);
    if (tsel == 0) {
      const float hA = tanhf(acc00) * (1.f - gA) + gA * tanhf(acc01);
      const float hB = tanhf(acc10) * (1.f - gB) + gB * tanhf(acc11);
      const int tl = k - lyr;
      if (tl >= 0 && tl < TT) {
        float* dst = p.hx + (size_t)((tl & 1) * GRP + g) * HBLK + seg + ug;
        sysstore(dst + (size_t)r0 * UP, hA);            // write-through to MALL
        sysstore(dst + (size_t)(r0 + 1) * UP, hB);
      }
    }

    // -- group barrier: relaxed arrive-counter, no cache maintenance --
    __syncthreads();   // drains vmcnt (sc0/sc1 stores acked at MALL) first
    if (k < TT + 2) {
      if (tid == 0) {
        int* ctr = p.ctr + g * 16;
        __hip_atomic_fetch_add(ctr, 1, __ATOMIC_RELAXED, __HIP_MEMORY_SCOPE_SYSTEM);
        const int tgt = WPG * (k + 1);
        while (__hip_atomic_load(ctr, __ATOMIC_RELAXED, __HIP_MEMORY_SCOPE_SYSTEM) < tgt)
          __builtin_amdgcn_s_sleep(2);
      }
      __syncthreads();
    }
  }
}

// in-place fc: out[b,t,:] = out[b,t,:] @ fc_w.T + fc_b  (pool is identity)
extern "C" __global__ void __launch_bounds__(256)
lnn_fc(float* out, const float* fcw, const float* fcb) {
  __shared__ float w[32 * 33];
  __shared__ float bb[32];
  __shared__ float tile[8 * 32];
  const int tid = threadIdx.x;
  for (int i = tid; i < 1024; i += 256) w[(i >> 5) * 33 + (i & 31)] = fcw[i];
  if (tid < 32) bb[tid] = fcb[tid];
  const size_t base = (size_t)blockIdx.x * 256;
  tile[tid] = out[base + tid];
  __syncthreads();
  const int pp = tid >> 5, o = tid & 31;
  float acc = bb[o];
  #pragma unroll
  for (int u = 0; u < 32; ++u) acc = fmaf(tile[pp * 32 + u], w[o * 33 + u], acc);
  out[base + pp * 32 + o] = acc;
}

extern "C" void kernel_launch(void* const* d_in, const int* in_sizes, int n_in,
                              void* d_out, int out_size, void* d_ws, size_t ws_size,
                              hipStream_t stream) {
  Params p;
  p.x = (const float*)d_in[0];
  const int wi[3] = {1, 10, 19};
  for (int l = 0; l < 3; ++l) {
    for (int m = 0; m < 4; ++m) {
      p.w[l][m] = (const float*)d_in[wi[l] + 2 * m];
      p.b[l][m] = (const float*)d_in[wi[l] + 2 * m + 1];
    }
  }
  p.mk[0] = (const int*)d_in[9];
  p.mk[1] = (const int*)d_in[18];
  p.mk[2] = (const int*)d_in[27];
  float* ws = (float*)d_ws;
  p.hx  = ws;
  p.ctr = (int*)(ws + CTR_OFF);
  p.out = (float*)d_out;

  hipFuncSetAttribute(reinterpret_cast<const void*>(lnn_main),
                      hipFuncAttributeMaxDynamicSharedMemorySize, SMEM_BYTES);
  hipMemsetAsync(d_ws, 0, (size_t)WS_DW * 4, stream);
  lnn_main<<<dim3(GRP * WPG), dim3(256), SMEM_BYTES, stream>>>(p);
  lnn_fc<<<dim3(NB * TT / 8), dim3(256), 0, stream>>>(
      (float*)d_out, (const float*)d_in[28], (const float*)d_in[29]);
}

// Round 4
// 5852.710 us; speedup vs baseline: 4.1048x; 2.0191x over previous
//
#include <hip/hip_runtime.h>
#include <cmath>

// ---------------------------------------------------------------------------
// Liquid NN (CfC) persistent-kernel implementation, R4.
//
// 32 groups x 8 WGs = 256 WGs (1/CU). Group owns 8 batch rows; WG owns 32
// units across the 3 layers -> 128 GEMM cols. Layer-skewed pipeline: tick k
// computes h0(k), h1(k-1), h2(k-2); one group barrier per tick.
// R4 vs R3 (R3's ~6us/tick barrier = 32 serialized fetch_add RMWs):
//  - flag-array barrier: per-WG flag store (no RMW) + 8-lane single-line
//    poll -> ~2 MALL round trips.
//  - group shrunk 32->8 WGs: h all-to-all traffic /4, 8 arrivals.
//  - weight LDS strides 276/244/148 (==20 mod 32) + per-row ((rid>>2)&7)*4
//    offset -> exactly 2-way (free) bank aliasing on GEMM weight reads
//    (R3's 4-way u-pair alias fixed).
//  - fast transcendentals (__expf + v_rcp tanh/sigmoid).
// ---------------------------------------------------------------------------

constexpr int TT   = 1024;
constexpr int NB   = 256;
constexpr int GRP  = 32;     // groups (8 batch rows each)
constexpr int WPG  = 8;      // WGs per group
constexpr int NU0  = 135, NU1 = 89, NU2 = 32;
constexpr int CAT0 = 263, CAT1 = 224, CAT2 = 121;
constexpr int U0P = 136, U1P = 92, U2P = 32;
// z-buffer row strides: z0=[x 128|h0 136]+4 ; z1=[h0 136|h1 92] ; z2=[h1 92|h2 32]
constexpr int KP0  = 268, KP1 = 228, KP2 = 124;
// weight LDS row strides, all ==20 mod 32 (with per-row shift -> 2-way max)
constexpr int WS0  = 276, WS1 = 244, WS2 = 148;

// LDS layout (dwords): 8 z rows per buffer
constexpr int ZB0s   = 0;
constexpr int ZB1s   = 8 * KP0;             // 2144
constexpr int ZB2s   = ZB1s + 8 * KP1;      // 3968
constexpr int WBASEs = ZB2s + 8 * KP2;      // 4960
// layer blocks padded +32 for per-row shift overhang; max over WG mixes (17,11,4)
constexpr int WMAXs  = 17*4*WS0 + 32 + 11*4*WS1 + 32 + 4*4*WS2 + 32;  // 31968
constexpr int BBASEs = WBASEs + WMAXs;      // 36928
constexpr int SMEM_DW    = BBASEs + 128;    // 37056
constexpr int SMEM_BYTES = SMEM_DW * 4;     // 148224

// exchange block per (parity,group): [h0 8x136 | h1 8x92 | h2 8x32]
constexpr int HBLK   = 8*U0P + 8*U1P + 8*U2P;   // 2080 floats = 520 f4
constexpr int SEG1   = 8*U0P;                    // 1088
constexpr int SEG2   = SEG1 + 8*U1P;             // 1824
constexpr int FLAG_OFF = 2 * GRP * HBLK;         // 133120 dwords
constexpr int WS_DW    = FLAG_OFF + GRP * 16;    // 133632

struct Params {
  const float* x;
  const float* w[3][4];
  const float* b[3][4];
  const int*   mk[3];
  float* hx;
  int*   flags;
  float* out;
};

__device__ __forceinline__ void sysstore(float* p, float v) {
  __hip_atomic_store(p, v, __ATOMIC_RELAXED, __HIP_MEMORY_SCOPE_SYSTEM);
}
// coherent (MALL-snooping) float4 load; value NOT ready until cwait()
__device__ __forceinline__ float4 cload(const float4* p) {
  float4 v;
  asm volatile("global_load_dwordx4 %0, %1, off sc0 sc1"
               : "=v"(v) : "v"(p) : "memory");
  return v;
}
__device__ __forceinline__ void cwait() {
  asm volatile("s_waitcnt vmcnt(0)" ::: "memory");
}
__device__ __forceinline__ float frcp(float x) { return __builtin_amdgcn_rcpf(x); }
__device__ __forceinline__ float ftanh(float x) {
  const float e = __expf(-2.f * fabsf(x));
  return copysignf((1.f - e) * frcp(1.f + e), x);
}

extern "C" __global__ void __launch_bounds__(256, 1)
lnn_main(Params p) {
  extern __shared__ float smem[];
  const int tid   = threadIdx.x;
  const int g     = blockIdx.x & 31;   // stride-32 peers share an XCD (heuristic)
  const int w_idx = blockIdx.x >> 5;   // 0..7 within group

  // ---- per-WG unit slices: WG0-6 get (17,11,4), WG7 gets (16,12,4) ---------
  const int n0  = (w_idx < 7) ? 17 : 16;
  const int us0 = w_idx * 17;
  const int n1  = (w_idx < 7) ? 11 : 12;
  const int us1 = w_idx * 11;
  const int us2 = w_idx * 4;
  const int L1B = n0 * 4 * WS0 + 32;            // lyr1 block base (in W region)
  const int L2B = L1B + n1 * 4 * WS1 + 32;      // lyr2 block base

  // ---- load weights (x mask) into LDS with padded-K remap + row shift ------
  for (int c = 0; c < 128; ++c) {
    const int s = c >> 2, m = c & 3;
    int lyr, rid, ug, cat, kpl, wst, lbase;
    if (s < n0)           { lyr = 0; rid = s*4 + m;            ug = us0 + s;           cat = CAT0; kpl = KP0; wst = WS0; lbase = 0;   }
    else if (s < n0 + n1) { lyr = 1; rid = (s - n0)*4 + m;     ug = us1 + (s - n0);    cat = CAT1; kpl = KP1; wst = WS1; lbase = L1B; }
    else                  { lyr = 2; rid = (s - n0 - n1)*4 + m; ug = us2 + (s - n0 - n1); cat = CAT2; kpl = KP2; wst = WS2; lbase = L2B; }
    const int wb = WBASEs + lbase + rid * wst + ((rid >> 2) & 7) * 4;
    const float* gw = p.w[lyr][m] + (size_t)ug * cat;
    const int*   gm = (m < 2) ? (p.mk[lyr] + (size_t)ug * cat) : nullptr;
    for (int kk = tid; kk < kpl; kk += 256) {
      int src;
      if (lyr == 0)      src = (kk < 263) ? kk : -1;
      else if (lyr == 1) src = (kk < 135) ? kk : (kk >= 136 && kk < 225) ? kk - 1 : -1;
      else               src = (kk < 89)  ? kk : (kk >= 92  && kk < 124) ? kk - 3 : -1;
      float v = 0.f;
      if (src >= 0) { v = gw[src]; if (gm) v *= (float)gm[src]; }
      smem[wb + kk] = v;
    }
  }
  if (tid < 128) {
    const int c = tid, s = c >> 2, m = c & 3;
    int lyr, ug;
    if (s < n0)           { lyr = 0; ug = us0 + s; }
    else if (s < n0 + n1) { lyr = 1; ug = us1 + (s - n0); }
    else                  { lyr = 2; ug = us2 + (s - n0 - n1); }
    smem[BBASEs + c] = p.b[lyr][m][ug];
  }
  if (tid < 8)   // one-time zero of z0 tail [264..267] per row
    for (int j = 264; j < 268; ++j) smem[tid * KP0 + j] = 0.f;
  __syncthreads();

  // ---- per-thread GEMM constants -------------------------------------------
  // thread tile 2 rows x 2 cols; wave = 4 row-pairs x 16 col-pairs
  const int wave = tid >> 6, lane = tid & 63;
  const int rp = lane & 3;
  const int cp = (lane >> 2) + 16 * wave;   // 0..63 col-pairs
  const int r0 = rp * 2;
  const int s    = cp >> 1;                 // unit slot 0..31
  const int tsel = cp & 1;                  // 0: (ff1,ff2)  1: (ta,tb)
  int lyr, u_loc;
  if (s < n0)           { lyr = 0; u_loc = s; }
  else if (s < n0 + n1) { lyr = 1; u_loc = s - n0; }
  else                  { lyr = 2; u_loc = s - n0 - n1; }
  const int ug  = (lyr == 0) ? us0 + u_loc : (lyr == 1) ? us1 + u_loc : us2 + u_loc;
  const int kp  = (lyr == 0) ? KP0 : (lyr == 1) ? KP1 : KP2;
  const int wst = (lyr == 0) ? WS0 : (lyr == 1) ? WS1 : WS2;
  const int zb  = (lyr == 0) ? ZB0s : (lyr == 1) ? ZB1s : ZB2s;
  const int lbase = (lyr == 0) ? 0 : (lyr == 1) ? L1B : L2B;
  const int rid0  = u_loc * 4 + tsel * 2;
  const int wb0 = WBASEs + lbase + rid0 * wst + ((rid0 >> 2) & 7) * 4;
  const int c0  = s * 4 + tsel * 2;
  const int seg = (lyr == 0) ? 0 : (lyr == 1) ? SEG1 : SEG2;
  const int UP  = (lyr == 0) ? U0P : (lyr == 1) ? U1P : U2P;
  const float bias0 = smem[BBASEs + c0];
  const float bias1 = smem[BBASEs + c0 + 1];

  // ---- tick loop: k = 0 .. TT+2 (A@k, B@k-1, C@k-2, out-copy@k-3) ----------
  for (int k = 0; k < TT + 3; ++k) {
    const int p0 = (k - 1) & 1;   // parity holding h0(k-1) / h2(k-3)
    const int p1 = k & 1;         // parity holding h1(k-2)

    // -- coherent h loads: f4 idx [0,272)=h0@p0, [272,456)=h1@p1, [456,520)=h2@p0
    const float4* hx0 = (const float4*)(p.hx + (size_t)(p0 * GRP + g) * HBLK);
    const float4* hx1 = (const float4*)(p.hx + (size_t)(p1 * GRP + g) * HBLK);
    const int i1 = tid + 256;
    const float4 hv0 = cload(hx0 + tid);   // tid<256 -> always h0 region
    const float4 hv1 = cload((i1 >= 272 && i1 < 456) ? hx1 + i1 : hx0 + i1);
    float4 hvt;
    if (tid < 8) hvt = cload(hx0 + 512 + tid);

    // -- x copy (plain loads) --
    const int tx = (k < TT) ? k : TT - 1;
    {
      const int r = tid >> 5, c4 = (tid & 31) * 4;
      const float4 v = *(const float4*)(p.x + ((size_t)(g * 8 + r) * TT + tx) * 128 + c4);
      *(float4*)(&smem[r * KP0 + c4]) = v;
    }

    cwait();

    // -- scatter h to LDS (dual stores for shared segments) --
    {
      const int r = tid / 34, c4 = (tid - r * 34) * 4;   // h0 part
      *(float4*)(&smem[r * KP0 + 128 + c4]) = hv0;
      *(float4*)(&smem[ZB1s + r * KP1 + c4]) = hv0;
    }
    if (i1 < 272) {
      const int r = i1 / 34, c4 = (i1 - r * 34) * 4;
      *(float4*)(&smem[r * KP0 + 128 + c4]) = hv1;
      *(float4*)(&smem[ZB1s + r * KP1 + c4]) = hv1;
    } else if (i1 < 456) {
      const int j = i1 - 272;
      const int r = j / 23, c4 = (j - r * 23) * 4;
      *(float4*)(&smem[ZB1s + r * KP1 + 136 + c4]) = hv1;
      *(float4*)(&smem[ZB2s + r * KP2 + c4]) = hv1;
    } else {
      const int j = i1 - 456;
      const int r = j >> 3, c4 = (j & 7) * 4;
      *(float4*)(&smem[ZB2s + r * KP2 + 92 + c4]) = hv1;
    }
    if (tid < 8) {
      const int j = tid + 56;                            // f4 idx 512..519
      const int r = j >> 3, c4 = (j & 7) * 4;
      *(float4*)(&smem[ZB2s + r * KP2 + 92 + c4]) = hvt;
    }
    __syncthreads();

    // -- coalesced out write: h2(k-3) assembled in z2; WG w owns row w --
    if (tid < 8 && k >= 3) {
      const float4 v = *(const float4*)(&smem[ZB2s + w_idx * KP2 + 92 + tid * 4]);
      *(float4*)(&p.out[((size_t)(g * 8 + w_idx) * TT + (k - 3)) * 32 + tid * 4]) = v;
    }

    // -- fused 8x128 GEMM (2r x 2c per thread) --
    float acc00 = bias0, acc01 = bias1, acc10 = bias0, acc11 = bias1;
    {
      const float* zp0 = &smem[zb + r0 * kp];
      const float* zp1 = zp0 + kp;
      const float* wp0 = &smem[wb0];
      const float* wp1 = wp0 + wst;
      #pragma unroll 8
      for (int kk = 0; kk < kp; kk += 4) {
        const float4 a0 = *(const float4*)(zp0 + kk);
        const float4 a1 = *(const float4*)(zp1 + kk);
        const float4 b0 = *(const float4*)(wp0 + kk);
        const float4 b1 = *(const float4*)(wp1 + kk);
        acc00 = fmaf(a0.x, b0.x, fmaf(a0.y, b0.y, fmaf(a0.z, b0.z, fmaf(a0.w, b0.w, acc00))));
        acc01 = fmaf(a0.x, b1.x, fmaf(a0.y, b1.y, fmaf(a0.z, b1.z, fmaf(a0.w, b1.w, acc01))));
        acc10 = fmaf(a1.x, b0.x, fmaf(a1.y, b0.y, fmaf(a1.z, b0.z, fmaf(a1.w, b0.w, acc10))));
        acc11 = fmaf(a1.x, b1.x, fmaf(a1.y, b1.y, fmaf(a1.z, b1.z, fmaf(a1.w, b1.w, acc11))));
      }
    }

    // -- combine: ta/tb thread -> sigmoid, shfl (lane+4) to ff thread --
    float sA = acc00 + acc01, sB = acc10 + acc11;
    sA = frcp(1.f + __expf(-sA));
    sB = frcp(1.f + __expf(-sB));
    const float gA = __shfl_down(sA, 4);
    const float gB = __shfl_down(sB, 4);
    if (tsel == 0) {
      const float hA = ftanh(acc00) * (1.f - gA) + gA * ftanh(acc01);
      const float hB = ftanh(acc10) * (1.f - gB) + gB * ftanh(acc11);
      const int tl = k - lyr;
      if (tl >= 0 && tl < TT) {
        float* dst = p.hx + (size_t)((tl & 1) * GRP + g) * HBLK + seg + ug;
        sysstore(dst + (size_t)r0 * UP, hA);            // write-through to MALL
        sysstore(dst + (size_t)(r0 + 1) * UP, hB);
      }
    }

    // -- group barrier: per-WG flag store (no RMW) + 8-lane single-line poll --
    __syncthreads();   // all waves drain vmcnt (h stores acked at MALL)
    if (tid == 0)
      __hip_atomic_store(&p.flags[g * 16 + w_idx], k + 1,
                         __ATOMIC_RELAXED, __HIP_MEMORY_SCOPE_SYSTEM);
    if (k < TT + 2) {
      if (tid < WPG) {
        const int* fp = &p.flags[g * 16 + tid];
        while (__hip_atomic_load(fp, __ATOMIC_RELAXED, __HIP_MEMORY_SCOPE_SYSTEM) < k + 1)
          __builtin_amdgcn_s_sleep(1);
      }
      __syncthreads();
    }
  }
}

// in-place fc: out[b,t,:] = out[b,t,:] @ fc_w.T + fc_b  (pool is identity)
extern "C" __global__ void __launch_bounds__(256)
lnn_fc(float* out, const float* fcw, const float* fcb) {
  __shared__ float w[32 * 33];
  __shared__ float bb[32];
  __shared__ float tile[8 * 32];
  const int tid = threadIdx.x;
  for (int i = tid; i < 1024; i += 256) w[(i >> 5) * 33 + (i & 31)] = fcw[i];
  if (tid < 32) bb[tid] = fcb[tid];
  const size_t base = (size_t)blockIdx.x * 256;
  tile[tid] = out[base + tid];
  __syncthreads();
  const int pp = tid >> 5, o = tid & 31;
  float acc = bb[o];
  #pragma unroll
  for (int u = 0; u < 32; ++u) acc = fmaf(tile[pp * 32 + u], w[o * 33 + u], acc);
  out[base + pp * 32 + o] = acc;
}

extern "C" void kernel_launch(void* const* d_in, const int* in_sizes, int n_in,
                              void* d_out, int out_size, void* d_ws, size_t ws_size,
                              hipStream_t stream) {
  Params p;
  p.x = (const float*)d_in[0];
  const int wi[3] = {1, 10, 19};
  for (int l = 0; l < 3; ++l) {
    for (int m = 0; m < 4; ++m) {
      p.w[l][m] = (const float*)d_in[wi[l] + 2 * m];
      p.b[l][m] = (const float*)d_in[wi[l] + 2 * m + 1];
    }
  }
  p.mk[0] = (const int*)d_in[9];
  p.mk[1] = (const int*)d_in[18];
  p.mk[2] = (const int*)d_in[27];
  float* ws = (float*)d_ws;
  p.hx    = ws;
  p.flags = (int*)(ws + FLAG_OFF);
  p.out   = (float*)d_out;

  hipFuncSetAttribute(reinterpret_cast<const void*>(lnn_main),
                      hipFuncAttributeMaxDynamicSharedMemorySize, SMEM_BYTES);
  hipMemsetAsync(d_ws, 0, (size_t)WS_DW * 4, stream);
  lnn_main<<<dim3(GRP * WPG), dim3(256), SMEM_BYTES, stream>>>(p);
  lnn_fc<<<dim3(NB * TT / 8), dim3(256), 0, stream>>>(
      (float*)d_out, (const float*)d_in[28], (const float*)d_in[29]);
}